// Round 1
// baseline (3044.158 us; speedup 1.0000x reference)
//
#include <hip/hip_runtime.h>

#define GAMMA_C 5.0f
#define COST_C 1e-3f
#define ITERS_C 200
#define ETA0_C 0.02f
#define B_C 128
#define H_C 12
#define N_C 128

__device__ __forceinline__ float sgnf(float x) {
    return (x > 0.f) ? 1.f : ((x < 0.f) ? -1.f : 0.f);
}

// Sigma[b,h] = L[b,h] @ L[b,h]^T   (one block per (b,h), 256 threads, 8x8 tile/thread)
__global__ __launch_bounds__(256) void sigma_kernel(const float* __restrict__ L,
                                                    float* __restrict__ Sigma) {
    __shared__ float Ls[N_C][N_C + 1];  // +1 pad to break bank conflicts
    const size_t base = (size_t)blockIdx.x * (N_C * N_C);
    const float* Lbh = L + base;
    for (int idx = threadIdx.x; idx < N_C * N_C; idx += 256) {
        Ls[idx >> 7][idx & 127] = Lbh[idx];
    }
    __syncthreads();
    const int ti = threadIdx.x >> 4, tj = threadIdx.x & 15;
    const int i0 = ti * 8, j0 = tj * 8;
    float acc[8][8];
#pragma unroll
    for (int x = 0; x < 8; ++x)
#pragma unroll
        for (int y = 0; y < 8; ++y) acc[x][y] = 0.f;
    for (int k = 0; k < N_C; ++k) {
        float a[8], bb[8];
#pragma unroll
        for (int d = 0; d < 8; ++d) {
            a[d] = Ls[i0 + d][k];
            bb[d] = Ls[j0 + d][k];
        }
#pragma unroll
        for (int x = 0; x < 8; ++x)
#pragma unroll
            for (int y = 0; y < 8; ++y) acc[x][y] = fmaf(a[x], bb[y], acc[x][y]);
    }
    float* Sbh = Sigma + base;
#pragma unroll
    for (int x = 0; x < 8; ++x)
#pragma unroll
        for (int y = 0; y < 8; ++y) Sbh[(size_t)(i0 + x) * N_C + (j0 + y)] = acc[x][y];
}

// One block per batch b. 12 waves; wave h owns time step h. 200 Jacobi iterations,
// one __syncthreads per iteration (double-buffered w in LDS).
// USE_SIGMA=1: M = precomputed Sigma (one matvec/iter).
// USE_SIGMA=0: M = L, compute z = L(L^T w) on the fly (fallback if ws too small).
template <int USE_SIGMA>
__global__ __launch_bounds__(768) void mpo_iterate(const float* __restrict__ mu,
                                                   const float* __restrict__ M,
                                                   const float* __restrict__ w_prev,
                                                   float* __restrict__ out) {
    const int b = blockIdx.x;
    const int h = threadIdx.x >> 6;
    const int lane = threadIdx.x & 63;
    const int c0 = lane * 2, c1 = c0 + 1;

    __shared__ float wbuf[2][H_C][N_C];
    __shared__ float wps[N_C];
    __shared__ float zbuf[H_C][N_C];  // only used by fallback path

    const size_t mbase = ((size_t)b * H_C + h) * (size_t)(N_C * N_C);
    const float* Mbh = M + mbase;
    const float mu0 = mu[((size_t)b * H_C + h) * N_C + c0];
    const float mu1 = mu[((size_t)b * H_C + h) * N_C + c1];

    if (threadIdx.x < N_C) wps[threadIdx.x] = w_prev[(size_t)b * N_C + threadIdx.x];
    wbuf[0][h][c0] = 1.f / N_C;
    wbuf[0][h][c1] = 1.f / N_C;
    __syncthreads();

    int p = 0;
    float nw0 = 1.f / N_C, nw1 = 1.f / N_C;

    for (int k = 0; k < ITERS_C; ++k) {
        const float* wrow = wbuf[p][h];
        float z0 = 0.f, z1 = 0.f;

        if (USE_SIGMA) {
            // z = Sigma w via symmetric column-broadcast: z[c] = sum_j w_j * S[j][c]
#pragma unroll 8
            for (int j = 0; j < N_C; ++j) {
                const float wj = wrow[j];
                const float2 sv = *(const float2*)(Mbh + (size_t)j * N_C + c0);
                z0 = fmaf(wj, sv.x, z0);
                z1 = fmaf(wj, sv.y, z1);
            }
        } else {
            // y = L^T w (lane-local cols), then z = L y (row-dot + wave reduce)
            float y0 = 0.f, y1 = 0.f;
#pragma unroll 8
            for (int j = 0; j < N_C; ++j) {
                const float wj = wrow[j];
                const float2 lv = *(const float2*)(Mbh + (size_t)j * N_C + c0);
                y0 = fmaf(wj, lv.x, y0);
                y1 = fmaf(wj, lv.y, y1);
            }
            for (int i = 0; i < N_C; ++i) {
                const float2 lv = *(const float2*)(Mbh + (size_t)i * N_C + c0);
                float part = lv.x * y0 + lv.y * y1;
#pragma unroll
                for (int d = 1; d < 64; d <<= 1) part += __shfl_xor(part, d);
                if (lane == (i & 63)) zbuf[h][i] = part;
            }
            __syncthreads();
            z0 = zbuf[h][c0];
            z1 = zbuf[h][c1];
        }

        const float w0 = wrow[c0], w1 = wrow[c1];
        float wp0, wp1;
        if (h == 0) {
            wp0 = wps[c0];
            wp1 = wps[c1];
        } else {
            wp0 = wbuf[p][h - 1][c0];
            wp1 = wbuf[p][h - 1][c1];
        }
        const float s0 = sgnf(w0 - wp0), s1 = sgnf(w1 - wp1);
        float sn0 = 0.f, sn1 = 0.f;
        if (h < H_C - 1) {
            sn0 = sgnf(wbuf[p][h + 1][c0] - w0);
            sn1 = sgnf(wbuf[p][h + 1][c1] - w1);
        }
        const float eta = ETA0_C / sqrtf((float)(k + 1));
        const float g0 = -mu0 + 2.f * GAMMA_C * z0 + COST_C * (s0 - sn0);
        const float g1 = -mu1 + 2.f * GAMMA_C * z1 + COST_C * (s1 - sn1);
        const float v0 = w0 - eta * g0;
        const float v1 = w1 - eta * g1;

        // Exact simplex projection: Michelot's algorithm (same theta as sort-based)
        float a0 = 1.f, a1 = 1.f, theta = 0.f;
        for (int it = 0; it < N_C; ++it) {
            float s = a0 * v0 + a1 * v1;
            float c = a0 + a1;
#pragma unroll
            for (int d = 1; d < 64; d <<= 1) {
                s += __shfl_xor(s, d);
                c += __shfl_xor(c, d);
            }
            theta = (s - 1.f) / c;
            const float na0 = (v0 > theta) ? 1.f : 0.f;
            const float na1 = (v1 > theta) ? 1.f : 0.f;
            const bool changed = (na0 != a0) || (na1 != a1);
            a0 = na0;
            a1 = na1;
            if (!__any(changed)) break;
        }
        nw0 = fmaxf(v0 - theta, 0.f);
        nw1 = fmaxf(v1 - theta, 0.f);
        wbuf[p ^ 1][h][c0] = nw0;
        wbuf[p ^ 1][h][c1] = nw1;
        __syncthreads();
        p ^= 1;
    }

    out[((size_t)b * H_C + h) * N_C + c0] = nw0;
    out[((size_t)b * H_C + h) * N_C + c1] = nw1;
}

extern "C" void kernel_launch(void* const* d_in, const int* in_sizes, int n_in,
                              void* d_out, int out_size, void* d_ws, size_t ws_size,
                              hipStream_t stream) {
    const float* mu = (const float*)d_in[0];
    const float* L = (const float*)d_in[1];
    const float* w_prev = (const float*)d_in[2];
    float* out = (float*)d_out;

    const size_t sigma_bytes = (size_t)B_C * H_C * N_C * N_C * sizeof(float);
    const bool use_sigma = (ws_size >= sigma_bytes) && (d_ws != nullptr);

    if (use_sigma) {
        float* Sigma = (float*)d_ws;
        sigma_kernel<<<B_C * H_C, 256, 0, stream>>>(L, Sigma);
        mpo_iterate<1><<<B_C, 768, 0, stream>>>(mu, Sigma, w_prev, out);
    } else {
        mpo_iterate<0><<<B_C, 768, 0, stream>>>(mu, L, w_prev, out);
    }
}

// Round 2
// 1695.842 us; speedup vs baseline: 1.7951x; 1.7951x over previous
//
#include <hip/hip_runtime.h>

#define GAMMA_C 5.0f
#define COST_C 1e-3f
#define ITERS_C 200
#define ETA0_C 0.02f
#define B_C 128
#define H_C 12
#define N_C 128
#define RR 80   // Sigma rows 0..RR-1 in registers (float2 per lane)
#define RL 48   // Sigma rows RR..127 in LDS
#define HPB 6   // time steps per block

__device__ __forceinline__ float sgnf(float x) {
    return (x > 0.f) ? 1.f : ((x < 0.f) ? -1.f : 0.f);
}
__device__ __forceinline__ float rdlane(float v, int l) {
    return __int_as_float(__builtin_amdgcn_readlane(__float_as_int(v), l));
}

// ---------------- Sigma[b,h] = L[b,h] @ L[b,h]^T ----------------
__global__ __launch_bounds__(256) void sigma_kernel(const float* __restrict__ L,
                                                    float* __restrict__ Sigma) {
    __shared__ float Ls[N_C][N_C + 1];
    const size_t base = (size_t)blockIdx.x * (N_C * N_C);
    const float* Lbh = L + base;
    for (int idx = threadIdx.x; idx < N_C * N_C; idx += 256) {
        Ls[idx >> 7][idx & 127] = Lbh[idx];
    }
    __syncthreads();
    const int ti = threadIdx.x >> 4, tj = threadIdx.x & 15;
    const int i0 = ti * 8, j0 = tj * 8;
    float acc[8][8];
#pragma unroll
    for (int x = 0; x < 8; ++x)
#pragma unroll
        for (int y = 0; y < 8; ++y) acc[x][y] = 0.f;
    for (int k = 0; k < N_C; ++k) {
        float a[8], bb[8];
#pragma unroll
        for (int d = 0; d < 8; ++d) {
            a[d] = Ls[i0 + d][k];
            bb[d] = Ls[j0 + d][k];
        }
#pragma unroll
        for (int x = 0; x < 8; ++x)
#pragma unroll
            for (int y = 0; y < 8; ++y) acc[x][y] = fmaf(a[x], bb[y], acc[x][y]);
    }
    float* Sbh = Sigma + base;
#pragma unroll
    for (int x = 0; x < 8; ++x)
#pragma unroll
        for (int y = 0; y < 8; ++y) Sbh[(size_t)(i0 + x) * N_C + (j0 + y)] = acc[x][y];
}

__global__ void init_flags(int* __restrict__ flags) {
    if (threadIdx.x < 2 * B_C) flags[threadIdx.x] = 0;
}

// ---------------- Resident iterate kernel ----------------
// 256 blocks x 384 threads. Block pair (b): halves A (h0-5) and B (h6-11).
// Pair mapping: bids n and n+8 -> same batch, same XCD (round-robin n%8).
// Sigma rows 0..RR-1 in VGPRs, RR..127 in LDS -> zero global traffic in loop.
// h5<->h6 coupling via double-buffered global slot + agent-scope flag sync.
__global__ __launch_bounds__(384, 2) void mpo_resident(
    const float* __restrict__ mu, const float* __restrict__ Sigma,
    const float* __restrict__ w_prev, float* __restrict__ out,
    float* __restrict__ wx, int* __restrict__ flags) {
    const int bid = blockIdx.x;
    const int b = (bid >> 4) * 8 + (bid & 7);  // batch 0..127
    const int half = (bid >> 3) & 1;           // 0: h0-5, 1: h6-11
    const int hw = threadIdx.x >> 6;           // wave id 0..5
    const int lane = threadIdx.x & 63;
    const int h = half * HPB + hw;
    const int c0 = lane * 2;

    __shared__ float slds[HPB][RL][N_C];   // 147456 B
    __shared__ float wbuf[2][HPB][N_C];    // 6144 B

    const float* Sbh = Sigma + (((size_t)b * H_C + h) << 14);

    // Load Sigma: rows 0..RR-1 into registers, RR..127 into LDS (coalesced float2)
    float2 sreg[RR];
#pragma unroll
    for (int j = 0; j < RR; ++j) sreg[j] = *(const float2*)(Sbh + (size_t)j * N_C + c0);
#pragma unroll
    for (int j = 0; j < RL; ++j) {
        float2 v = *(const float2*)(Sbh + (size_t)(RR + j) * N_C + c0);
        *(float2*)&slds[hw][j][c0] = v;
    }

    const float mu0 = mu[((size_t)b * H_C + h) * N_C + c0];
    const float mu1 = mu[((size_t)b * H_C + h) * N_C + c0 + 1];
    float wp0 = 0.f, wp1 = 0.f;
    if (hw == 0 && half == 0) {
        wp0 = w_prev[(size_t)b * N_C + c0];
        wp1 = w_prev[(size_t)b * N_C + c0 + 1];
    }

    float* wx_own = wx + (size_t)(b * 2 + half) * 2 * N_C;
    const float* wx_par = wx + (size_t)(b * 2 + (half ^ 1)) * 2 * N_C;
    int* flag_own = flags + b * 2 + half;
    int* flag_par = flags + b * 2 + (half ^ 1);

    float w0 = 1.f / N_C, w1 = 1.f / N_C;
    wbuf[0][hw][c0] = w0;
    wbuf[0][hw][c0 + 1] = w1;
    __syncthreads();

    int p = 0;
    const bool is_bA = (half == 0 && hw == HPB - 1);  // produces w5, consumes w6
    const bool is_bB = (half == 1 && hw == 0);        // produces w6, consumes w5

    for (int k = 0; k < ITERS_C; ++k) {
        // ---- z = Sigma w : register rows + LDS rows, w via readlane (SGPR) ----
        float za0 = 0.f, za1 = 0.f, zb0 = 0.f, zb1 = 0.f;
#pragma unroll
        for (int j = 0; j < RR; j += 2) {
            const float wj0 = rdlane(w0, j >> 1);  // w[j]   (j even)
            const float wj1 = rdlane(w1, j >> 1);  // w[j+1]
            za0 = fmaf(wj0, sreg[j].x, za0);
            za1 = fmaf(wj0, sreg[j].y, za1);
            zb0 = fmaf(wj1, sreg[j + 1].x, zb0);
            zb1 = fmaf(wj1, sreg[j + 1].y, zb1);
        }
#pragma unroll
        for (int j = 0; j < RL; j += 2) {
            const int jj = RR + j;
            const float wj0 = rdlane(w0, jj >> 1);
            const float wj1 = rdlane(w1, jj >> 1);
            const float2 sa = *(const float2*)&slds[hw][j][c0];
            const float2 sb = *(const float2*)&slds[hw][j + 1][c0];
            za0 = fmaf(wj0, sa.x, za0);
            za1 = fmaf(wj0, sa.y, za1);
            zb0 = fmaf(wj1, sb.x, zb0);
            zb1 = fmaf(wj1, sb.y, zb1);
        }
        const float z0 = za0 + zb0;
        const float z1 = za1 + zb1;

        // ---- neighbor w for sign terms ----
        float wm0, wm1;
        if (hw > 0) {
            wm0 = wbuf[p][hw - 1][c0];
            wm1 = wbuf[p][hw - 1][c0 + 1];
        } else if (half == 0) {
            wm0 = wp0;
            wm1 = wp1;
        } else {
            if (k == 0) {
                wm0 = 1.f / N_C;
                wm1 = 1.f / N_C;
            } else {
                while (__hip_atomic_load(flag_par, __ATOMIC_ACQUIRE,
                                         __HIP_MEMORY_SCOPE_AGENT) < k)
                    __builtin_amdgcn_s_sleep(2);
                const float* src = wx_par + (size_t)(k & 1) * N_C;
                wm0 = __hip_atomic_load(src + c0, __ATOMIC_RELAXED, __HIP_MEMORY_SCOPE_AGENT);
                wm1 = __hip_atomic_load(src + c0 + 1, __ATOMIC_RELAXED, __HIP_MEMORY_SCOPE_AGENT);
            }
        }
        float sn0 = 0.f, sn1 = 0.f;
        if (hw < HPB - 1) {
            const float wn0 = wbuf[p][hw + 1][c0];
            const float wn1 = wbuf[p][hw + 1][c0 + 1];
            sn0 = sgnf(wn0 - w0);
            sn1 = sgnf(wn1 - w1);
        } else if (half == 0) {
            float wn0, wn1;
            if (k == 0) {
                wn0 = 1.f / N_C;
                wn1 = 1.f / N_C;
            } else {
                while (__hip_atomic_load(flag_par, __ATOMIC_ACQUIRE,
                                         __HIP_MEMORY_SCOPE_AGENT) < k)
                    __builtin_amdgcn_s_sleep(2);
                const float* src = wx_par + (size_t)(k & 1) * N_C;
                wn0 = __hip_atomic_load(src + c0, __ATOMIC_RELAXED, __HIP_MEMORY_SCOPE_AGENT);
                wn1 = __hip_atomic_load(src + c0 + 1, __ATOMIC_RELAXED, __HIP_MEMORY_SCOPE_AGENT);
            }
            sn0 = sgnf(wn0 - w0);
            sn1 = sgnf(wn1 - w1);
        }
        const float s0 = sgnf(w0 - wm0), s1 = sgnf(w1 - wm1);

        const float eta = ETA0_C / sqrtf((float)(k + 1));
        const float v0 = w0 - eta * (-mu0 + 2.f * GAMMA_C * z0 + COST_C * (s0 - sn0));
        const float v1 = w1 - eta * (-mu1 + 2.f * GAMMA_C * z1 + COST_C * (s1 - sn1));

        // ---- exact simplex projection (Michelot) ----
        float a0 = 1.f, a1 = 1.f, theta = 0.f;
        for (int it = 0; it < N_C; ++it) {
            float s = a0 * v0 + a1 * v1;
            float c = a0 + a1;
#pragma unroll
            for (int d = 1; d < 64; d <<= 1) {
                s += __shfl_xor(s, d);
                c += __shfl_xor(c, d);
            }
            theta = (s - 1.f) / c;
            const float na0 = (v0 > theta) ? 1.f : 0.f;
            const float na1 = (v1 > theta) ? 1.f : 0.f;
            const bool changed = (na0 != a0) || (na1 != a1);
            a0 = na0;
            a1 = na1;
            if (!__any(changed)) break;
        }
        w0 = fmaxf(v0 - theta, 0.f);
        w1 = fmaxf(v1 - theta, 0.f);

        wbuf[p ^ 1][hw][c0] = w0;
        wbuf[p ^ 1][hw][c0 + 1] = w1;

        if (is_bA || is_bB) {
            float* dst = wx_own + (size_t)((k + 1) & 1) * N_C;
            __hip_atomic_store(dst + c0, w0, __ATOMIC_RELAXED, __HIP_MEMORY_SCOPE_AGENT);
            __hip_atomic_store(dst + c0 + 1, w1, __ATOMIC_RELAXED, __HIP_MEMORY_SCOPE_AGENT);
            // per-lane release orders each lane's own data stores before its flag store
            __hip_atomic_store(flag_own, k + 1, __ATOMIC_RELEASE, __HIP_MEMORY_SCOPE_AGENT);
        }
        __syncthreads();
        p ^= 1;
    }

    out[((size_t)b * H_C + h) * N_C + c0] = w0;
    out[((size_t)b * H_C + h) * N_C + c0 + 1] = w1;
}

// ---------------- Round-1 fallback (streaming) ----------------
template <int USE_SIGMA>
__global__ __launch_bounds__(768) void mpo_iterate(const float* __restrict__ mu,
                                                   const float* __restrict__ M,
                                                   const float* __restrict__ w_prev,
                                                   float* __restrict__ out) {
    const int b = blockIdx.x;
    const int h = threadIdx.x >> 6;
    const int lane = threadIdx.x & 63;
    const int c0 = lane * 2, c1 = c0 + 1;

    __shared__ float wbuf[2][H_C][N_C];
    __shared__ float wps[N_C];
    __shared__ float zbuf[H_C][N_C];

    const size_t mbase = ((size_t)b * H_C + h) * (size_t)(N_C * N_C);
    const float* Mbh = M + mbase;
    const float mu0 = mu[((size_t)b * H_C + h) * N_C + c0];
    const float mu1 = mu[((size_t)b * H_C + h) * N_C + c1];

    if (threadIdx.x < N_C) wps[threadIdx.x] = w_prev[(size_t)b * N_C + threadIdx.x];
    wbuf[0][h][c0] = 1.f / N_C;
    wbuf[0][h][c1] = 1.f / N_C;
    __syncthreads();

    int p = 0;
    float nw0 = 1.f / N_C, nw1 = 1.f / N_C;

    for (int k = 0; k < ITERS_C; ++k) {
        const float* wrow = wbuf[p][h];
        float z0 = 0.f, z1 = 0.f;

        if (USE_SIGMA) {
#pragma unroll 8
            for (int j = 0; j < N_C; ++j) {
                const float wj = wrow[j];
                const float2 sv = *(const float2*)(Mbh + (size_t)j * N_C + c0);
                z0 = fmaf(wj, sv.x, z0);
                z1 = fmaf(wj, sv.y, z1);
            }
        } else {
            float y0 = 0.f, y1 = 0.f;
#pragma unroll 8
            for (int j = 0; j < N_C; ++j) {
                const float wj = wrow[j];
                const float2 lv = *(const float2*)(Mbh + (size_t)j * N_C + c0);
                y0 = fmaf(wj, lv.x, y0);
                y1 = fmaf(wj, lv.y, y1);
            }
            for (int i = 0; i < N_C; ++i) {
                const float2 lv = *(const float2*)(Mbh + (size_t)i * N_C + c0);
                float part = lv.x * y0 + lv.y * y1;
#pragma unroll
                for (int d = 1; d < 64; d <<= 1) part += __shfl_xor(part, d);
                if (lane == (i & 63)) zbuf[h][i] = part;
            }
            __syncthreads();
            z0 = zbuf[h][c0];
            z1 = zbuf[h][c1];
        }

        const float w0 = wrow[c0], w1 = wrow[c1];
        float wp0, wp1;
        if (h == 0) {
            wp0 = wps[c0];
            wp1 = wps[c1];
        } else {
            wp0 = wbuf[p][h - 1][c0];
            wp1 = wbuf[p][h - 1][c1];
        }
        const float s0 = sgnf(w0 - wp0), s1 = sgnf(w1 - wp1);
        float sn0 = 0.f, sn1 = 0.f;
        if (h < H_C - 1) {
            sn0 = sgnf(wbuf[p][h + 1][c0] - w0);
            sn1 = sgnf(wbuf[p][h + 1][c1] - w1);
        }
        const float eta = ETA0_C / sqrtf((float)(k + 1));
        const float g0 = -mu0 + 2.f * GAMMA_C * z0 + COST_C * (s0 - sn0);
        const float g1 = -mu1 + 2.f * GAMMA_C * z1 + COST_C * (s1 - sn1);
        const float v0 = w0 - eta * g0;
        const float v1 = w1 - eta * g1;

        float a0 = 1.f, a1 = 1.f, theta = 0.f;
        for (int it = 0; it < N_C; ++it) {
            float s = a0 * v0 + a1 * v1;
            float c = a0 + a1;
#pragma unroll
            for (int d = 1; d < 64; d <<= 1) {
                s += __shfl_xor(s, d);
                c += __shfl_xor(c, d);
            }
            theta = (s - 1.f) / c;
            const float na0 = (v0 > theta) ? 1.f : 0.f;
            const float na1 = (v1 > theta) ? 1.f : 0.f;
            const bool changed = (na0 != a0) || (na1 != a1);
            a0 = na0;
            a1 = na1;
            if (!__any(changed)) break;
        }
        nw0 = fmaxf(v0 - theta, 0.f);
        nw1 = fmaxf(v1 - theta, 0.f);
        wbuf[p ^ 1][h][c0] = nw0;
        wbuf[p ^ 1][h][c1] = nw1;
        __syncthreads();
        p ^= 1;
    }

    out[((size_t)b * H_C + h) * N_C + c0] = nw0;
    out[((size_t)b * H_C + h) * N_C + c1] = nw1;
}

extern "C" void kernel_launch(void* const* d_in, const int* in_sizes, int n_in,
                              void* d_out, int out_size, void* d_ws, size_t ws_size,
                              hipStream_t stream) {
    const float* mu = (const float*)d_in[0];
    const float* L = (const float*)d_in[1];
    const float* w_prev = (const float*)d_in[2];
    float* out = (float*)d_out;

    const size_t sigma_elems = (size_t)B_C * H_C * N_C * N_C;
    const size_t sigma_bytes = sigma_elems * sizeof(float);
    const size_t wx_elems = (size_t)B_C * 2 * 2 * N_C;  // batches x halves x dblbuf x N
    const size_t need = sigma_bytes + (wx_elems + 2 * B_C) * sizeof(float);

    if (ws_size >= need && d_ws != nullptr) {
        float* Sigma = (float*)d_ws;
        float* wxp = Sigma + sigma_elems;
        int* flags = (int*)(wxp + wx_elems);
        init_flags<<<1, 256, 0, stream>>>(flags);
        sigma_kernel<<<B_C * H_C, 256, 0, stream>>>(L, Sigma);
        mpo_resident<<<2 * B_C, 384, 0, stream>>>(mu, Sigma, w_prev, out, wxp, flags);
    } else if (ws_size >= sigma_bytes && d_ws != nullptr) {
        float* Sigma = (float*)d_ws;
        sigma_kernel<<<B_C * H_C, 256, 0, stream>>>(L, Sigma);
        mpo_iterate<1><<<B_C, 768, 0, stream>>>(mu, Sigma, w_prev, out);
    } else {
        mpo_iterate<0><<<B_C, 768, 0, stream>>>(mu, L, w_prev, out);
    }
}